// Round 3
// baseline (393.546 us; speedup 1.0000x reference)
//
#include <hip/hip_runtime.h>
#include <hip/hip_bf16.h>
#include <math.h>

// Fused SpectralPooling: out = (A (x) A (x) A) * x per (b,c) volume,
// A[j][n] = sum_{k<28} D32[k][j] * D64[k][n]  (32x64).
// V,U contractions on MFMA bf16; final n-contraction fp32 VALU (skewed 1 iter).
// Barriers are raw "s_waitcnt lgkmcnt(0); s_barrier" so global prefetch loads
// stay in flight across them (compiler's __syncthreads drains vmcnt(0)).

typedef short short8 __attribute__((ext_vector_type(8)));
typedef float f32x4 __attribute__((ext_vector_type(4)));

__global__ void init_A(float* __restrict__ ws) {
    int g = blockIdx.x * blockDim.x + threadIdx.x;  // 0..2047
    if (g >= 2048) return;
    int j = g >> 6;   // 0..31
    int n = g & 63;   // 0..63
    const double PI = 3.14159265358979323846;
    double acc = 0.0;
    for (int k = 0; k < 28; ++k) {
        double s32 = (k == 0) ? sqrt(1.0 / 32.0) : sqrt(2.0 / 32.0);
        double s64 = (k == 0) ? sqrt(1.0 / 64.0) : sqrt(2.0 / 64.0);
        acc += s32 * cos(PI * (2.0 * j + 1.0) * (double)k / 64.0)
             * s64 * cos(PI * (2.0 * n + 1.0) * (double)k / 128.0);
    }
    ws[g] = (float)acc;                 // A  row-major [32][64]
    ws[2048 + n * 32 + j] = (float)acc; // At row-major [64][32]
}

__device__ inline unsigned pk_bf16(float a, float b) {
    union { __hip_bfloat162 h2; unsigned u; } c;
    c.h2 = __float22bfloat162_rn(make_float2(a, b));
    return c.u;
}

// LDS-only barrier: orders LDS traffic across the workgroup WITHOUT draining
// vmcnt — global prefetch loads remain in flight across it.
__device__ inline void lds_barrier() {
    asm volatile("s_waitcnt lgkmcnt(0)\n\ts_barrier" ::: "memory");
}

// grid = 256 blocks (one per (b,c) volume), 512 threads (8 waves).
__global__ __launch_bounds__(512, 2) void spectral_kernel(
    const float* __restrict__ x, const float* __restrict__ ws,
    float* __restrict__ out)
{
    __shared__ __align__(16) unsigned short Xbf[2][64][72]; // x slabs bf16 (18.4 KB)
    __shared__ __align__(16) unsigned short Vbf[2][32][72]; // v[k][m] bf16 ( 9.2 KB)
    __shared__ __align__(16) float          Ubuf[2][32][36];// u[j][k] fp32 ( 9.2 KB)
    __shared__ __align__(16) unsigned short Abf[32][72];    // A bf16       ( 4.6 KB)
    __shared__ __align__(16) float          Atl[64][32];    // At fp32      ( 8.2 KB)

    const int t    = threadIdx.x;
    const int b    = blockIdx.x;
    const int lane = t & 63;
    const int l15  = lane & 15;
    const int q4   = lane >> 4;                              // quad 0..3
    const int w    = __builtin_amdgcn_readfirstlane(t >> 6); // wave 0..7
    const int sl   = w & 1;                                  // slab
    const int ws4  = w >> 1;                                 // 0..3
    const int m0   = ws4 * 16;                               // phase-V m-tile
    const int kt2  = ws4 & 1;                                // phase-U k-tile
    const int jt   = ws4 >> 1;                               // phase-U j-tile
    const int k32  = t & 31;
    const int j0   = t >> 5;                                 // 0..15

    const float4* xsrc = (const float4*)(x + (size_t)b * 262144);

    // depth-2 register prefetch: ra = slab-pair 0, rb = slab-pair 1
    float4 ra[4], rb[4];
#pragma unroll
    for (int ri = 0; ri < 4; ++ri) ra[ri] = xsrc[t + 512 * ri];
#pragma unroll
    for (int ri = 0; ri < 4; ++ri) rb[ri] = xsrc[2048 + t + 512 * ri];

    // ---- stage A (bf16) and At (fp32) into LDS ----
    {
        const float* Ag  = ws;
        const float* Atg = ws + 2048;
        for (int q = t; q < 2048; q += 512) {
            float v = Ag[q];
            __hip_bfloat16 h = __float2bfloat16(v);
            Abf[q >> 6][q & 63] = *(unsigned short*)&h;
            ((float*)Atl)[q] = Atg[q];
        }
    }

    float acc0[32], acc1[32];
#pragma unroll
    for (int i = 0; i < 32; ++i) { acc0[i] = 0.f; acc1[i] = 0.f; }

    lds_barrier();  // A/At staged

    // constant B-fragments of A (shared by phases V and U), kept in VGPRs:
    // bv[r][c]: element j = A[r*16 + l15][c*32 + q4*8 + j]
    short8 bv00 = *(const short8*)&Abf[l15][q4 * 8];
    short8 bv01 = *(const short8*)&Abf[l15][32 + q4 * 8];
    short8 bv10 = *(const short8*)&Abf[16 + l15][q4 * 8];
    short8 bv11 = *(const short8*)&Abf[16 + l15][32 + q4 * 8];

    auto body = [&](int it, float4* r) {
        // ---- stage pair it into LDS (fp32 -> bf16) ----
#pragma unroll
        for (int ri = 0; ri < 4; ++ri) {
            int q = t + 512 * ri;
            *(uint2*)&Xbf[q >> 10][(q >> 4) & 63][(q & 15) * 4] =
                make_uint2(pk_bf16(r[ri].x, r[ri].y), pk_bf16(r[ri].z, r[ri].w));
        }
        lds_barrier();  // B1: staging visible; prior U writes of Ubuf visible

        // issue prefetch for pair it+2 (stays in flight across B2)
        if (it + 2 < 32) {
#pragma unroll
            for (int ri = 0; ri < 4; ++ri)
                r[ri] = xsrc[(it + 2) * 2048 + t + 512 * ri];
        }

        // ---- phase ACC(it-1), fp32 VALU, overlaps the in-flight prefetch ----
        if (it > 0) {
            float u00 = Ubuf[0][j0][k32];
            float u01 = Ubuf[0][j0 + 16][k32];
            float u10 = Ubuf[1][j0][k32];
            float u11 = Ubuf[1][j0 + 16][k32];
            const float4* c0p = (const float4*)&Atl[2 * (it - 1)][0];
            const float4* c1p = (const float4*)&Atl[2 * (it - 1) + 1][0];
#pragma unroll
            for (int i4 = 0; i4 < 8; ++i4) {
                float4 c0 = c0p[i4];
                float4 c1 = c1p[i4];
                acc0[i4 * 4 + 0] += c0.x * u00 + c1.x * u10;
                acc0[i4 * 4 + 1] += c0.y * u00 + c1.y * u10;
                acc0[i4 * 4 + 2] += c0.z * u00 + c1.z * u10;
                acc0[i4 * 4 + 3] += c0.w * u00 + c1.w * u10;
                acc1[i4 * 4 + 0] += c0.x * u01 + c1.x * u11;
                acc1[i4 * 4 + 1] += c0.y * u01 + c1.y * u11;
                acc1[i4 * 4 + 2] += c0.z * u01 + c1.z * u11;
                acc1[i4 * 4 + 3] += c0.w * u01 + c1.w * u11;
            }
        }

        // ---- phase V (MFMA): v[m][k] = sum_p X[m][p] * A[k][p] ----
        {
            short8 xa0 = *(const short8*)&Xbf[sl][m0 + l15][q4 * 8];
            short8 xa1 = *(const short8*)&Xbf[sl][m0 + l15][32 + q4 * 8];
            f32x4 z = {0.f, 0.f, 0.f, 0.f};
            f32x4 v0 = __builtin_amdgcn_mfma_f32_16x16x32_bf16(xa0, bv00, z, 0, 0, 0);
            v0 = __builtin_amdgcn_mfma_f32_16x16x32_bf16(xa1, bv01, v0, 0, 0, 0);
            f32x4 v1 = __builtin_amdgcn_mfma_f32_16x16x32_bf16(xa0, bv10, z, 0, 0, 0);
            v1 = __builtin_amdgcn_mfma_f32_16x16x32_bf16(xa1, bv11, v1, 0, 0, 0);
            // D: row m = m0 + q4*4 + reg, col k = l15 (+16) -> Vbf[sl][k][m] bf16
            *(uint2*)&Vbf[sl][l15][m0 + q4 * 4] =
                make_uint2(pk_bf16(v0.x, v0.y), pk_bf16(v0.z, v0.w));
            *(uint2*)&Vbf[sl][16 + l15][m0 + q4 * 4] =
                make_uint2(pk_bf16(v1.x, v1.y), pk_bf16(v1.z, v1.w));
        }
        lds_barrier();  // B2: Vbf visible; V reads of Xbf done (next staging safe)

        // ---- phase U (MFMA): u[k][j] = sum_m v[k][m] * A[j][m] ----
        {
            short8 va0 = *(const short8*)&Vbf[sl][kt2 * 16 + l15][q4 * 8];
            short8 va1 = *(const short8*)&Vbf[sl][kt2 * 16 + l15][32 + q4 * 8];
            f32x4 z = {0.f, 0.f, 0.f, 0.f};
            f32x4 u = __builtin_amdgcn_mfma_f32_16x16x32_bf16(
                va0, jt ? bv10 : bv00, z, 0, 0, 0);
            u = __builtin_amdgcn_mfma_f32_16x16x32_bf16(
                va1, jt ? bv11 : bv01, u, 0, 0, 0);
            // D: row k = kt2*16 + q4*4 + reg, col j = jt*16 + l15
            *(float4*)&Ubuf[sl][jt * 16 + l15][kt2 * 16 + q4 * 4] =
                make_float4(u.x, u.y, u.z, u.w);
        }
        // (no barrier here; B1 of next iteration orders Ubuf for ACC)
    };

    for (int it2 = 0; it2 < 32; it2 += 2) {
        body(it2, ra);
        body(it2 + 1, rb);
    }

    lds_barrier();  // final U writes visible

    // ---- ACC(31) drain ----
    {
        float u00 = Ubuf[0][j0][k32];
        float u01 = Ubuf[0][j0 + 16][k32];
        float u10 = Ubuf[1][j0][k32];
        float u11 = Ubuf[1][j0 + 16][k32];
        const float4* c0p = (const float4*)&Atl[62][0];
        const float4* c1p = (const float4*)&Atl[63][0];
#pragma unroll
        for (int i4 = 0; i4 < 8; ++i4) {
            float4 c0 = c0p[i4];
            float4 c1 = c1p[i4];
            acc0[i4 * 4 + 0] += c0.x * u00 + c1.x * u10;
            acc0[i4 * 4 + 1] += c0.y * u00 + c1.y * u10;
            acc0[i4 * 4 + 2] += c0.z * u00 + c1.z * u10;
            acc0[i4 * 4 + 3] += c0.w * u00 + c1.w * u10;
            acc1[i4 * 4 + 0] += c0.x * u01 + c1.x * u11;
            acc1[i4 * 4 + 1] += c0.y * u01 + c1.y * u11;
            acc1[i4 * 4 + 2] += c0.z * u01 + c1.z * u11;
            acc1[i4 * 4 + 3] += c0.w * u01 + c1.w * u11;
        }
    }

    // ---- epilogue: out[b][i][j][k] ----
    float* ob = out + (size_t)b * 32768;
#pragma unroll
    for (int i = 0; i < 32; ++i) {
        ob[i * 1024 + j0 * 32 + k32]        = acc0[i];
        ob[i * 1024 + (j0 + 16) * 32 + k32] = acc1[i];
    }
}

extern "C" void kernel_launch(void* const* d_in, const int* in_sizes, int n_in,
                              void* d_out, int out_size, void* d_ws, size_t ws_size,
                              hipStream_t stream) {
    const float* x = (const float*)d_in[0];
    float* out = (float*)d_out;
    float* ws  = (float*)d_ws;   // [0,2048): A ; [2048,4096): At

    init_A<<<2, 1024, 0, stream>>>(ws);
    spectral_kernel<<<256, 512, 0, stream>>>(x, ws, out);
}